// Round 1
// baseline (407.473 us; speedup 1.0000x reference)
//
#include <hip/hip_runtime.h>
#include <math.h>

// GroupSorter: B=512 groups, N=64 rows/group, C=1024 features, fp32.
// rel[n] = mean_m gn[n]·gn[m] = gn[n]·(Σ_m gn[m])/N  — sim matrix collapsed.
// fp64 accumulation throughout so ordering matches the numpy reference's
// rel values to ~1e-13 (row-swap on a near-tie is the only way to fail the
// 0.108 absmax threshold; fp32 re-rounding would double that risk).

constexpr int Bq = 512;
constexpr int Nq = 64;
constexpr int Cq = 1024;
constexpr int C4 = Cq / 4;            // 256 float4 per row
constexpr int G4 = Nq * C4;           // 16384 float4 per group
constexpr int OUT_HALF4 = Bq * G4;    // float4 offset of out_input half

__global__ __launch_bounds__(256)
void group_sorter_kernel(const float* __restrict__ feats, float* __restrict__ out) {
    __shared__ float  s_lds[Cq];      // fp32 copy of weighted column sum
    __shared__ double rnorm[Nq];      // 1/max(||g_n||, 1e-12)
    __shared__ double rel[Nq];        // relation score (unnormalized by 1/N: positive scale preserves order)
    __shared__ int    dst_row[Nq];    // rank of row n = its output position

    const int b    = blockIdx.x;
    const int t    = threadIdx.x;
    const int wave = t >> 6;
    const int lane = t & 63;

    const float4* __restrict__ g4 =
        reinterpret_cast<const float4*>(feats) + (size_t)b * G4;

    // ---- Pass 1: row L2 norms (fp64), one row per wave-iteration -------------
    for (int n = wave; n < Nq; n += 4) {
        const float4* row = g4 + n * C4;
        double acc = 0.0;
        #pragma unroll
        for (int j = 0; j < 4; ++j) {
            float4 v = row[lane + 64 * j];
            acc += (double)v.x * v.x + (double)v.y * v.y
                 + (double)v.z * v.z + (double)v.w * v.w;
        }
        #pragma unroll
        for (int off = 32; off > 0; off >>= 1) acc += __shfl_xor(acc, off, 64);
        if (lane == 0) rnorm[n] = 1.0 / fmax(sqrt(acc), 1e-12);
    }
    __syncthreads();

    // ---- Pass 2: s[c] = Σ_m g[m][c] * rnorm[m]; thread t owns cols 4t..4t+3 --
    {
        double s0 = 0, s1 = 0, s2 = 0, s3 = 0;
        for (int m = 0; m < Nq; ++m) {
            float4 v = g4[m * C4 + t];      // coalesced: 256 threads = one row
            double rn = rnorm[m];           // LDS broadcast
            s0 += (double)v.x * rn; s1 += (double)v.y * rn;
            s2 += (double)v.z * rn; s3 += (double)v.w * rn;
        }
        reinterpret_cast<float4*>(s_lds)[t] =
            make_float4((float)s0, (float)s1, (float)s2, (float)s3);
    }
    __syncthreads();

    // ---- Pass 3: rel[n] = (g[n]·s) * rnorm[n] --------------------------------
    {
        const float4* s4 = reinterpret_cast<const float4*>(s_lds);
        for (int n = wave; n < Nq; n += 4) {
            const float4* row = g4 + n * C4;
            double acc = 0.0;
            #pragma unroll
            for (int j = 0; j < 4; ++j) {
                float4 v  = row[lane + 64 * j];
                float4 sv = s4[lane + 64 * j];   // 16B/lane contiguous: conflict-free
                acc += (double)v.x * sv.x + (double)v.y * sv.y
                     + (double)v.z * sv.z + (double)v.w * sv.w;
            }
            #pragma unroll
            for (int off = 32; off > 0; off >>= 1) acc += __shfl_xor(acc, off, 64);
            if (lane == 0) rel[n] = acc * rnorm[n];
        }
    }
    __syncthreads();

    // ---- Ranks: stable descending (ties -> lower index first), O(N^2) --------
    if (t < Nq) {
        double mine = rel[t];
        int r = 0;
        for (int m = 0; m < Nq; ++m) {
            double o = rel[m];
            r += (o > mine) || (o == mine && m < t);
        }
        dst_row[t] = r;   // order[dst_row[n]] == n
    }
    __syncthreads();

    // ---- Pass 4: one read feeds both outputs; writes fully coalesced ---------
    float4* os = reinterpret_cast<float4*>(out) + (size_t)b * G4;              // out_sorted
    float4* oi = reinterpret_cast<float4*>(out) + OUT_HALF4 + (size_t)b * G4;  // out_input
    for (int i = 0; i < Nq; ++i) {
        int f = i * C4 + t;               // 256 threads cover exactly row i
        float4 v = g4[f];                 // L2/L3-hot (4th read of this group)
        oi[f] = v;
        os[dst_row[i] * C4 + t] = v;      // whole wave writes one dst row: coalesced
    }
}

extern "C" void kernel_launch(void* const* d_in, const int* in_sizes, int n_in,
                              void* d_out, int out_size, void* d_ws, size_t ws_size,
                              hipStream_t stream) {
    const float* feats = (const float*)d_in[0];
    float* out = (float*)d_out;
    // labels (d_in[1]) encode the static contiguous-uniform grouping; unused.
    hipLaunchKernelGGL(group_sorter_kernel, dim3(Bq), dim3(256), 0, stream,
                       feats, out);
}

// Round 2
// 398.026 us; speedup vs baseline: 1.0237x; 1.0237x over previous
//
#include <hip/hip_runtime.h>
#include <math.h>

// GroupSorter: B=512 groups, N=64 rows/group, C=1024 features, fp32.
// rel[n] = mean_m gn[n]·gn[m] = gn[n]·(Σ_m gn[m]/N) — sim matrix collapsed to
// one weighted column-sum + one dot per row. fp64 accumulation so the sort
// order matches the numpy reference exactly (near-tie row swap is the only
// way to blow the absmax threshold).
//
// R2: 1024-thread blocks (32 waves/CU vs R1's 8 — R1 was latency-bound at
// OccupancyPercent≈10, 407µs vs 61µs BW floor); out_input copy fused into
// the pass that already touches every element; non-temporal output stores so
// 256MB of writes don't evict the group's 256KB from L2 between passes.

constexpr int Bq = 512;
constexpr int Nq = 64;
constexpr int Cq = 1024;
constexpr int C4 = Cq / 4;            // 256 float4 per row
constexpr int G4 = Nq * C4;           // 16384 float4 per group
constexpr int OUT_HALF4 = Bq * G4;    // float4 offset of out_input half

typedef float f4 __attribute__((ext_vector_type(4)));

__global__ __launch_bounds__(1024)
void group_sorter_kernel(const float* __restrict__ feats, float* __restrict__ out) {
    __shared__ double sp[4][C4][4];   // pass-2 partials: [part][col4][comp] = 32 KB
    __shared__ float  s_lds[Cq];      // fp32 weighted column sum
    __shared__ double rnorm[Nq];      // 1/max(||g_n||, 1e-12)
    __shared__ double rel[Nq];        // relation score (×N scale: order-preserving)
    __shared__ int    dst_row[Nq];    // output position of source row n

    const int b    = blockIdx.x;
    const int t    = threadIdx.x;
    const int wave = t >> 6;          // 0..15
    const int lane = t & 63;

    const f4* __restrict__ g4 = reinterpret_cast<const f4*>(feats) + (size_t)b * G4;
    f4* __restrict__ os = reinterpret_cast<f4*>(out) + (size_t)b * G4;              // out_sorted
    f4* __restrict__ oi = reinterpret_cast<f4*>(out) + OUT_HALF4 + (size_t)b * G4;  // out_input

    // ---- Pass 1: row L2 norms (fp64); 16 waves cover 64 rows, 4 rows/wave ----
    for (int n = wave; n < Nq; n += 16) {
        const f4* row = g4 + n * C4;
        double acc = 0.0;
        #pragma unroll
        for (int j = 0; j < 4; ++j) {
            f4 v = row[lane + 64 * j];
            acc += (double)v.x * v.x + (double)v.y * v.y
                 + (double)v.z * v.z + (double)v.w * v.w;
        }
        #pragma unroll
        for (int off = 32; off > 0; off >>= 1) acc += __shfl_xor(acc, off, 64);
        if (lane == 0) rnorm[n] = 1.0 / fmax(sqrt(acc), 1e-12);
    }
    __syncthreads();

    // ---- Pass 2: s[c] = Σ_m g[m][c]·rnorm[m], 4-way row-split; fused oi copy -
    {
        const int part = t >> 8;      // 0..3 -> rows part*16 .. part*16+15
        const int c4   = t & 255;
        double s0 = 0, s1 = 0, s2 = 0, s3 = 0;
        #pragma unroll 4
        for (int mm = 0; mm < 16; ++mm) {
            const int m = part * 16 + mm;
            f4 v = g4[m * C4 + c4];               // coalesced; each element read once
            double rn = rnorm[m];
            s0 += (double)v.x * rn; s1 += (double)v.y * rn;
            s2 += (double)v.z * rn; s3 += (double)v.w * rn;
            __builtin_nontemporal_store(v, &oi[m * C4 + c4]);  // out_input, bypass L2
        }
        sp[part][c4][0] = s0; sp[part][c4][1] = s1;
        sp[part][c4][2] = s2; sp[part][c4][3] = s3;
    }
    __syncthreads();
    {   // reduce the 4 partials; thread t owns column (t>>2, comp t&3)
        const int c4 = t >> 2, comp = t & 3;
        double sum = sp[0][c4][comp] + sp[1][c4][comp]
                   + sp[2][c4][comp] + sp[3][c4][comp];
        s_lds[c4 * 4 + comp] = (float)sum;
    }
    __syncthreads();

    // ---- Pass 3: rel[n] = (g[n]·s) * rnorm[n]  (reads L2-hot) ----------------
    {
        const f4* s4 = reinterpret_cast<const f4*>(s_lds);
        for (int n = wave; n < Nq; n += 16) {
            const f4* row = g4 + n * C4;
            double acc = 0.0;
            #pragma unroll
            for (int j = 0; j < 4; ++j) {
                f4 v  = row[lane + 64 * j];
                f4 sv = s4[lane + 64 * j];        // 16B/lane contiguous: conflict-free
                acc += (double)v.x * sv.x + (double)v.y * sv.y
                     + (double)v.z * sv.z + (double)v.w * sv.w;
            }
            #pragma unroll
            for (int off = 32; off > 0; off >>= 1) acc += __shfl_xor(acc, off, 64);
            if (lane == 0) rel[n] = acc * rnorm[n];
        }
    }
    __syncthreads();

    // ---- Ranks: stable descending count (ties -> lower index first) ----------
    if (t < Nq) {
        double mine = rel[t];
        int r = 0;
        for (int m = 0; m < Nq; ++m) {
            double o = rel[m];
            r += (o > mine) || (o == mine && m < t);
        }
        dst_row[t] = r;
    }
    __syncthreads();

    // ---- Pass 4: sorted scatter; reads L2-hot, writes row-coalesced ----------
    {
        const int rsub = t >> 8;      // 4 rows per iteration
        const int c4   = t & 255;
        #pragma unroll 4
        for (int i4 = 0; i4 < 16; ++i4) {
            const int i = i4 * 4 + rsub;
            f4 v = g4[i * C4 + c4];
            __builtin_nontemporal_store(v, &os[dst_row[i] * C4 + c4]);
        }
    }
}

extern "C" void kernel_launch(void* const* d_in, const int* in_sizes, int n_in,
                              void* d_out, int out_size, void* d_ws, size_t ws_size,
                              hipStream_t stream) {
    const float* feats = (const float*)d_in[0];
    float* out = (float*)d_out;
    // labels (d_in[1]) encode the static contiguous-uniform grouping; unused.
    hipLaunchKernelGGL(group_sorter_kernel, dim3(Bq), dim3(1024), 0, stream,
                       feats, out);
}